// Round 3
// 865.765 us; speedup vs baseline: 1.0081x; 1.0081x over previous
//
#include <hip/hip_runtime.h>
#include <hip/hip_bf16.h>

typedef __bf16 bf16;
typedef __attribute__((ext_vector_type(2))) __fp16 f16x2;
typedef __attribute__((ext_vector_type(4))) __bf16 bf16x4;
typedef __attribute__((ext_vector_type(8))) __bf16 bf16x8;
typedef __attribute__((ext_vector_type(4))) float floatx4;

#define BB 8
#define NN 4096
#define MM 2048
#define DD 256
#define DV 256

// async 16B global -> LDS (wave-uniform LDS base + lane*16 placement)
__device__ __forceinline__ void async_copy16(const void* g, void* l) {
    __builtin_amdgcn_global_load_lds(
        (const __attribute__((address_space(1))) unsigned int*)g,
        (__attribute__((address_space(3))) unsigned int*)l, 16, 0, 0);
}

// ---------------------------------------------------------------------------
// Kernel 1: transpose v [B][M][DV] fp32 -> vT [B][DV][M] bf16 (in d_ws)
// ---------------------------------------------------------------------------
__global__ __launch_bounds__(256) void vtrans_kernel(const float* __restrict__ v,
                                                     bf16* __restrict__ vT) {
    const int b  = blockIdx.z;
    const int m0 = blockIdx.y * 64;
    const int d0 = blockIdx.x * 64;
    __shared__ float Ts[64][65];
    const int t  = threadIdx.x;
    const int cf = t & 15;
    const int r  = t >> 4;

    const float* vb = v + ((size_t)b * MM + m0) * DV + d0;
    for (int p = 0; p < 4; ++p) {
        int row = p * 16 + r;
        float4 x = *(const float4*)(vb + (size_t)row * DV + cf * 4);
        Ts[row][cf * 4 + 0] = x.x;
        Ts[row][cf * 4 + 1] = x.y;
        Ts[row][cf * 4 + 2] = x.z;
        Ts[row][cf * 4 + 3] = x.w;
    }
    __syncthreads();
    bf16* ob = vT + ((size_t)b * DV + d0) * MM + m0;
    for (int p = 0; p < 4; ++p) {
        int dv = p * 16 + r;
        bf16x4 w;
        for (int i = 0; i < 4; ++i) w[i] = (bf16)Ts[cf * 4 + i][dv];
        *(bf16x4*)(ob + (size_t)dv * MM + cf * 4) = w;
    }
}

// ---------------------------------------------------------------------------
// Kernel 1b: elementwise fp32 -> bf16 with scale (for q/16 and k)
// ---------------------------------------------------------------------------
__global__ __launch_bounds__(256) void conv_kernel(const float* __restrict__ src,
                                                   bf16* __restrict__ dst,
                                                   float scale) {
    size_t i = ((size_t)blockIdx.x * 256 + threadIdx.x) * 8;
    float4 a = *(const float4*)(src + i);
    float4 b = *(const float4*)(src + i + 4);
    bf16x8 w;
    w[0] = (bf16)(a.x * scale); w[1] = (bf16)(a.y * scale);
    w[2] = (bf16)(a.z * scale); w[3] = (bf16)(a.w * scale);
    w[4] = (bf16)(b.x * scale); w[5] = (bf16)(b.y * scale);
    w[6] = (bf16)(b.z * scale); w[7] = (bf16)(b.w * scale);
    *(bf16x8*)(dst + i) = w;
}

// ---------------------------------------------------------------------------
// Kernel 2 (fast): S = qbf @ kbf^T, both operands pre-converted bf16 in ws.
// m97-style: global_load_lds width-16 into unpadded [128][64] LDS tiles.
// ---------------------------------------------------------------------------
__global__ __launch_bounds__(256) void qk_fast_kernel(const bf16* __restrict__ qbf,
                                                      const bf16* __restrict__ kbf,
                                                      float* __restrict__ S) {
    const int b  = blockIdx.z;
    const int n0 = blockIdx.y * 128;
    const int m0 = blockIdx.x * 128;

    __shared__ bf16 As[128 * 64];
    __shared__ bf16 Bs[128 * 64];

    const int tid  = threadIdx.x;
    const int lane = tid & 63;
    const int wave = tid >> 6;
    const int wr   = (wave & 1) * 64;
    const int wc   = (wave >> 1) * 64;
    const int l15  = lane & 15;
    const int quad = lane >> 4;

    floatx4 acc[4][4] = {};

    const bf16* qb = qbf + ((size_t)b * NN + n0) * DD;
    const bf16* kb = kbf + ((size_t)b * MM + m0) * DD;

    const int lrow = lane >> 3;        // 0..7
    const int lcol = (lane & 7) * 8;   // elem col within 64-chunk

    for (int k0 = 0; k0 < DD; k0 += 64) {
        __syncthreads();
        for (int p = 0; p < 4; ++p) {
            int seg = wave * 4 + p;            // 0..15
            int row = seg * 8 + lrow;          // 0..127
            async_copy16(qb + (size_t)row * DD + k0 + lcol, &As[seg * 512]);
            async_copy16(kb + (size_t)row * DD + k0 + lcol, &Bs[seg * 512]);
        }
        __syncthreads();
        for (int kk = 0; kk < 64; kk += 32) {
            bf16x8 af[4], bfv[4];
            for (int i = 0; i < 4; ++i)
                af[i] = *(const bf16x8*)&As[(wr + i * 16 + l15) * 64 + kk + quad * 8];
            for (int j = 0; j < 4; ++j)
                bfv[j] = *(const bf16x8*)&Bs[(wc + j * 16 + l15) * 64 + kk + quad * 8];
            for (int i = 0; i < 4; ++i)
                for (int j = 0; j < 4; ++j)
                    acc[i][j] = __builtin_amdgcn_mfma_f32_16x16x32_bf16(
                        af[i], bfv[j], acc[i][j], 0, 0, 0);
        }
    }

    float* Sb = S + ((size_t)b * NN + n0) * MM + m0;
    for (int i = 0; i < 4; ++i)
        for (int j = 0; j < 4; ++j) {
            int gc = wc + j * 16 + l15;
            for (int r = 0; r < 4; ++r) {
                int gr = wr + i * 16 + quad * 4 + r;
                Sb[(size_t)gr * MM + gc] = acc[i][j][r];
            }
        }
}

// ---------------------------------------------------------------------------
// Kernel 2 (fallback, ws too small): fp32 inputs staged with VALU convert.
// ---------------------------------------------------------------------------
__global__ __launch_bounds__(256) void qk_kernel(const float* __restrict__ q,
                                                 const float* __restrict__ k,
                                                 float* __restrict__ S) {
    const int b  = blockIdx.z;
    const int n0 = blockIdx.y * 128;
    const int m0 = blockIdx.x * 128;

    __shared__ bf16 As[128][72];
    __shared__ bf16 Bs[128][72];

    const int tid  = threadIdx.x;
    const int lane = tid & 63;
    const int wave = tid >> 6;
    const int wr   = (wave & 1) * 64;
    const int wc   = (wave >> 1) * 64;
    const int l15  = lane & 15;
    const int quad = lane >> 4;

    floatx4 acc[4][4] = {};

    const float* qb = q + ((size_t)b * NN + n0) * DD;
    const float* kb = k + ((size_t)b * MM + m0) * DD;

    const int cf = tid & 15;
    const int rr = tid >> 4;

    for (int k0 = 0; k0 < DD; k0 += 64) {
        __syncthreads();
        for (int p = 0; p < 8; ++p) {
            int row = p * 16 + rr;
            float4 aq = *(const float4*)(qb + (size_t)row * DD + k0 + cf * 4);
            float4 bk = *(const float4*)(kb + (size_t)row * DD + k0 + cf * 4);
            bf16x4 wa, wb;
            wa[0] = (bf16)(aq.x * 0.0625f);
            wa[1] = (bf16)(aq.y * 0.0625f);
            wa[2] = (bf16)(aq.z * 0.0625f);
            wa[3] = (bf16)(aq.w * 0.0625f);
            wb[0] = (bf16)bk.x;
            wb[1] = (bf16)bk.y;
            wb[2] = (bf16)bk.z;
            wb[3] = (bf16)bk.w;
            *(bf16x4*)&As[row][cf * 4] = wa;
            *(bf16x4*)&Bs[row][cf * 4] = wb;
        }
        __syncthreads();
        for (int kk = 0; kk < 64; kk += 32) {
            bf16x8 af[4], bfv[4];
            for (int i = 0; i < 4; ++i)
                af[i] = *(const bf16x8*)&As[wr + i * 16 + l15][kk + quad * 8];
            for (int j = 0; j < 4; ++j)
                bfv[j] = *(const bf16x8*)&Bs[wc + j * 16 + l15][kk + quad * 8];
            for (int i = 0; i < 4; ++i)
                for (int j = 0; j < 4; ++j)
                    acc[i][j] = __builtin_amdgcn_mfma_f32_16x16x32_bf16(
                        af[i], bfv[j], acc[i][j], 0, 0, 0);
        }
    }

    float* Sb = S + ((size_t)b * NN + n0) * MM + m0;
    for (int i = 0; i < 4; ++i)
        for (int j = 0; j < 4; ++j) {
            int gc = wc + j * 16 + l15;
            for (int r = 0; r < 4; ++r) {
                int gr = wr + i * 16 + quad * 4 + r;
                Sb[(size_t)gr * MM + gc] = acc[i][j][r];
            }
        }
}

// ---------------------------------------------------------------------------
// Kernel 3: attn = softmax(mask ? S : -1e9) + softmax(oa), in place.
// ONE WAVE PER ROW. v2: row state held as PACKED f16 pairs (32 VGPRs instead
// of 64) so the arrays stay in VGPRs (no AGPR shuffling) and occupancy rises;
// sched_barrier every 2 chunks caps load hoisting so in-flight load regs stay
// bounded (TLP over ILP). exp inputs ~N(0,1), outputs <=~0.05, so f16 RTZ
// error (<=1e-3 rel) contributes <=1e-5 to attn — far below tolerance.
// ---------------------------------------------------------------------------
__global__ __launch_bounds__(256) void softmax_add_kernel(const float* __restrict__ oa,
                                                          const int* __restrict__ mask,
                                                          float* __restrict__ attn) {
    const int lane = threadIdx.x & 63;
    const int wv   = threadIdx.x >> 6;
    const size_t base = ((size_t)blockIdx.x * 4 + wv) * MM;

    f16x2 sh[16], oh[16];
    float mxs = -1e30f, mxo = -1e30f;

    // phase 1: oa -> packed f16, running max
#pragma unroll
    for (int c = 0; c < 8; ++c) {
        const size_t off = base + c * 256 + lane * 4;
        float4 o4 = *(const float4*)(oa + off);
        mxo = fmaxf(mxo, fmaxf(fmaxf(o4.x, o4.y), fmaxf(o4.z, o4.w)));
        oh[c * 2 + 0] = __builtin_amdgcn_cvt_pkrtz(o4.x, o4.y);
        oh[c * 2 + 1] = __builtin_amdgcn_cvt_pkrtz(o4.z, o4.w);
        if (c & 1) __builtin_amdgcn_sched_barrier(0);
    }
    // phase 2: S + mask -> packed f16 (masked = -60: exp(-60-mx) == 0.f), max
#pragma unroll
    for (int c = 0; c < 8; ++c) {
        const size_t off = base + c * 256 + lane * 4;
        float4 s4 = *(const float4*)(attn + off);
        int4   m4 = *(const int4*)(mask + off);
        float a0 = m4.x ? s4.x : -60.0f;
        float a1 = m4.y ? s4.y : -60.0f;
        float a2 = m4.z ? s4.z : -60.0f;
        float a3 = m4.w ? s4.w : -60.0f;
        mxs = fmaxf(mxs, fmaxf(fmaxf(a0, a1), fmaxf(a2, a3)));
        sh[c * 2 + 0] = __builtin_amdgcn_cvt_pkrtz(a0, a1);
        sh[c * 2 + 1] = __builtin_amdgcn_cvt_pkrtz(a2, a3);
        if (c & 1) __builtin_amdgcn_sched_barrier(0);
    }

#pragma unroll
    for (int off = 32; off >= 1; off >>= 1) {
        mxs = fmaxf(mxs, __shfl_xor(mxs, off, 64));
        mxo = fmaxf(mxo, __shfl_xor(mxo, off, 64));
    }

    float sums = 0.f, sumo = 0.f;
#pragma unroll
    for (int i = 0; i < 16; ++i) {
        float s0 = (float)sh[i][0], s1 = (float)sh[i][1];
        float o0 = (float)oh[i][0], o1 = (float)oh[i][1];
        s0 = __expf(s0 - mxs); s1 = __expf(s1 - mxs);
        o0 = __expf(o0 - mxo); o1 = __expf(o1 - mxo);
        sums += s0 + s1;
        sumo += o0 + o1;
        sh[i] = __builtin_amdgcn_cvt_pkrtz(s0, s1);   // exp in [0,1]: f16-safe
        oh[i] = __builtin_amdgcn_cvt_pkrtz(o0, o1);
    }
#pragma unroll
    for (int off = 32; off >= 1; off >>= 1) {
        sums += __shfl_xor(sums, off, 64);
        sumo += __shfl_xor(sumo, off, 64);
    }

    const float invs = 1.0f / sums;
    const float invo = 1.0f / sumo;
#pragma unroll
    for (int c = 0; c < 8; ++c) {
        float4 w;
        w.x = (float)sh[c * 2 + 0][0] * invs + (float)oh[c * 2 + 0][0] * invo;
        w.y = (float)sh[c * 2 + 0][1] * invs + (float)oh[c * 2 + 0][1] * invo;
        w.z = (float)sh[c * 2 + 1][0] * invs + (float)oh[c * 2 + 1][0] * invo;
        w.w = (float)sh[c * 2 + 1][1] * invs + (float)oh[c * 2 + 1][1] * invo;
        *(float4*)(attn + base + c * 256 + lane * 4) = w;
    }
}

// ---------------------------------------------------------------------------
// Kernel 4: out = attn @ v.  64(n) x 256(full DV) tile, 256 threads.
// v2: attn staged RAW fp32 via global_load_lds (no VALU staging, no VGPR
// round-trip), converted to bf16 at fragment-read time. Both LDS tiles use a
// 16B-chunk XOR swizzle (chunk ^= row&7) applied on BOTH the global source
// address (global_load_lds writes linearly) and the ds_read side — kills the
// 16-way bank conflict of the linear layouts.
// ---------------------------------------------------------------------------
__global__ __launch_bounds__(256) void pv_kernel(const float* __restrict__ attn,
                                                 const bf16* __restrict__ vT,
                                                 float* __restrict__ out) {
    const int b  = blockIdx.y;
    const int n0 = blockIdx.x * 64;

    __shared__ float As[64 * 64];    // 16 KB fp32 attn tile (chunk-swizzled)
    __shared__ bf16  Bs[256 * 64];   // 32 KB bf16 vT tile (chunk-swizzled)

    const int tid  = threadIdx.x;
    const int lane = tid & 63;
    const int wave = tid >> 6;
    const int wc   = wave * 64;      // dv quarter per wave
    const int l15  = lane & 15;
    const int quad = lane >> 4;

    floatx4 acc[4][4] = {};

    const float* ab  = attn + ((size_t)b * NN + n0) * MM;
    const bf16*  vtb = vT + (size_t)b * DV * MM;

    for (int k0 = 0; k0 < MM; k0 += 64) {
        __syncthreads();
        // stage As: 1024 chunks of 16B; slot s -> row r=s>>4, lds-chunk ch=s&15,
        // source chunk g = ch ^ (r&7)  (XOR involution, pre-swizzled source)
        for (int p = 0; p < 4; ++p) {
            int s  = (wave * 4 + p) * 64 + lane;
            int r  = s >> 4;
            int g  = (s & 15) ^ (r & 7);
            async_copy16(ab + (size_t)r * MM + k0 + g * 4,
                         &As[(wave * 4 + p) * 256]);
        }
        // stage Bs: 2048 chunks of 16B; slot s -> row r=s>>3, ch=s&7,
        // source chunk g = ch ^ (r&7)
        for (int p = 0; p < 8; ++p) {
            int s  = (wave * 8 + p) * 64 + lane;
            int r  = s >> 3;
            int g  = (s & 7) ^ (r & 7);
            async_copy16(vtb + (size_t)r * MM + k0 + g * 8,
                         &Bs[(wave * 8 + p) * 512]);
        }
        __syncthreads();
        for (int kk = 0; kk < 64; kk += 32) {
            bf16x8 af[4], bfv[4];
            for (int i = 0; i < 4; ++i) {
                int row = i * 16 + l15;
                int c0  = (kk >> 2) + quad * 2;          // 16B chunk (4 floats)
                float4 x = *(const float4*)&As[row * 64 + (((c0    ) ^ (row & 7)) << 2)];
                float4 y = *(const float4*)&As[row * 64 + (((c0 + 1) ^ (row & 7)) << 2)];
                bf16x8 a;
                a[0] = (bf16)x.x; a[1] = (bf16)x.y; a[2] = (bf16)x.z; a[3] = (bf16)x.w;
                a[4] = (bf16)y.x; a[5] = (bf16)y.y; a[6] = (bf16)y.z; a[7] = (bf16)y.w;
                af[i] = a;
            }
            for (int j = 0; j < 4; ++j) {
                int row = wc + j * 16 + l15;
                int c0  = (kk >> 3) + quad;              // 16B chunk (8 bf16)
                bfv[j] = *(const bf16x8*)&Bs[row * 64 + ((c0 ^ (row & 7)) << 3)];
            }
            for (int i = 0; i < 4; ++i)
                for (int j = 0; j < 4; ++j)
                    acc[i][j] = __builtin_amdgcn_mfma_f32_16x16x32_bf16(
                        af[i], bfv[j], acc[i][j], 0, 0, 0);
        }
    }

    float* ob = out + ((size_t)b * NN + n0) * DV;
    for (int i = 0; i < 4; ++i)
        for (int j = 0; j < 4; ++j) {
            int gc = wc + j * 16 + l15;
            for (int r = 0; r < 4; ++r) {
                int gr = i * 16 + quad * 4 + r;
                ob[(size_t)gr * DV + gc] = acc[i][j][r];
            }
        }
}

extern "C" void kernel_launch(void* const* d_in, const int* in_sizes, int n_in,
                              void* d_out, int out_size, void* d_ws, size_t ws_size,
                              hipStream_t stream) {
    const float* q    = (const float*)d_in[0];
    const float* k    = (const float*)d_in[1];
    const float* v    = (const float*)d_in[2];
    const float* oa   = (const float*)d_in[3];
    const int*   mask = (const int*)d_in[4];

    float* out  = (float*)d_out;
    float* attn = out + (size_t)BB * NN * DV;  // raw S, then final attn (in place)

    // ws layout: vT (8 MB) | qbf (16 MB) | kbf (8 MB)
    bf16* vT  = (bf16*)d_ws;
    bf16* qbf = (bf16*)((char*)d_ws + (size_t)8 * 1024 * 1024);
    bf16* kbf = (bf16*)((char*)d_ws + (size_t)24 * 1024 * 1024);
    const bool fast = ws_size >= (size_t)32 * 1024 * 1024;

    vtrans_kernel<<<dim3(DV / 64, MM / 64, BB), 256, 0, stream>>>(v, vT);
    if (fast) {
        conv_kernel<<<(BB * NN * DD / 8 + 255) / 256, 256, 0, stream>>>(q, qbf, 0.0625f);
        conv_kernel<<<(BB * MM * DD / 8 + 255) / 256, 256, 0, stream>>>(k, kbf, 1.0f);
        qk_fast_kernel<<<dim3(MM / 128, NN / 128, BB), 256, 0, stream>>>(qbf, kbf, attn);
    } else {
        qk_kernel<<<dim3(MM / 128, NN / 128, BB), 256, 0, stream>>>(q, k, attn);
    }
    softmax_add_kernel<<<BB * NN / 4, 256, 0, stream>>>(oa, mask, attn);
    pv_kernel<<<dim3(NN / 64, BB), 256, 0, stream>>>(attn, vT, out);
}